// Round 2
// baseline (1181.383 us; speedup 1.0000x reference)
//
#include <hip/hip_runtime.h>
#include <math.h>

#define BATCH     512
#define T_PAST_   360
#define T_FUT_    1800
#define IN_SZ     3
#define H_SZ      64
#define FUT_SEQ   50
#define WSPF_     34
#define MAX_STEPS (FUT_SEQ * WSPF_)      // 1700
#define T_TOT     (T_PAST_ + MAX_STEPS)  // 2060
#define NGATES    (4 * H_SZ)             // 256

__device__ __forceinline__ float sigmoid_(float x) {
    return 1.0f / (1.0f + __expf(-x));
}

__device__ __forceinline__ float tanh_(float x) {
    float a = fabsf(x);
    float e = __expf(-2.0f * a);         // in (0,1]
    float t = (1.0f - e) / (1.0f + e);
    return copysignf(t, x);
}

__global__ __launch_bounds__(NGATES, 2)
void lstm_fused_kernel(const float* __restrict__ wave_input,   // [B, 360, 3]
                       const float* __restrict__ wave_future,  // [B, 1800, 3]
                       const float* __restrict__ W_ih,         // [256, 3]
                       const float* __restrict__ W_hh,         // [256, 64]
                       const float* __restrict__ b_ih,         // [256]
                       const float* __restrict__ b_hh,         // [256]
                       const float* __restrict__ W_proj,       // [64, 64]
                       const float* __restrict__ b_proj,       // [64]
                       float* __restrict__ out)                // [B, 50, 64]
{
    __shared__ __align__(16) float x_lds[T_TOT * IN_SZ];   // 24.7 KB
    __shared__ __align__(16) float wproj_lds[H_SZ * 65];   // 16.6 KB, padded
    __shared__ __align__(16) float gates_lds[2][NGATES];   // double-buffered, 2 KB
    __shared__ __align__(16) float h_lds[4][H_SZ];         // per-wave private copy, 1 KB
    __shared__ __align__(16) float bproj_lds[H_SZ];

    const int b    = blockIdx.x;
    const int tid  = threadIdx.x;
    const int wv   = tid >> 6;    // wave id 0..3
    const int lane = tid & 63;

    // ---- stage this batch element's input sequence into LDS (coalesced) ----
    {
        const float* wi = wave_input + (size_t)b * (T_PAST_ * IN_SZ);
        for (int i = tid; i < T_PAST_ * IN_SZ; i += NGATES) x_lds[i] = wi[i];
        const float* wf = wave_future + (size_t)b * (T_FUT_ * IN_SZ);
        for (int i = tid; i < MAX_STEPS * IN_SZ; i += NGATES)
            x_lds[T_PAST_ * IN_SZ + i] = wf[i];
    }
    // ---- W_proj into LDS, padded stride 65 -> conflict-free column reads ----
    for (int i = tid; i < H_SZ * H_SZ; i += NGATES) {
        int r = i >> 6, cc = i & 63;
        wproj_lds[r * 65 + cc] = W_proj[i];
    }
    if (tid < H_SZ) bproj_lds[tid] = b_proj[tid];
    h_lds[wv][lane] = 0.0f;       // every (wave,lane) pair covered exactly once

    // ---- per-thread recurrent weights: row `tid` of W_hh in 64 VGPRs ----
    float whh[H_SZ];
    {
        const float4* row = (const float4*)(W_hh + tid * H_SZ);
        #pragma unroll
        for (int j = 0; j < 16; ++j) {
            float4 v = row[j];
            whh[4 * j + 0] = v.x; whh[4 * j + 1] = v.y;
            whh[4 * j + 2] = v.z; whh[4 * j + 3] = v.w;
        }
    }
    const float wih0 = W_ih[tid * 3 + 0];
    const float wih1 = W_ih[tid * 3 + 1];
    const float wih2 = W_ih[tid * 3 + 2];
    const float bg   = b_ih[tid] + b_hh[tid];
    const bool  gate_is_tanh = (tid >= 2 * H_SZ) && (tid < 3 * H_SZ);  // g-gate

    // Every thread redundantly maintains c[lane] (per-wave copy) so the h
    // update is within-wave -> no second barrier per step.
    float c = 0.0f;
    float* outb  = out + (size_t)b * (FUT_SEQ * H_SZ);
    int next_cp = T_PAST_ + WSPF_ - 1;    // first checkpoint t = 393
    int cp_k = 0;

    __syncthreads();

    for (int t = 0; t < T_TOT; ++t) {
        // ---- phase A: gate pre-activation (own wave's h copy, broadcast) ----
        float x0 = x_lds[t * 3 + 0];
        float x1 = x_lds[t * 3 + 1];
        float x2 = x_lds[t * 3 + 2];

        const float4* h4 = (const float4*)h_lds[wv];
        float a0 = fmaf(wih0, x0, bg);
        float a1 = fmaf(wih1, x1, 0.0f);
        float a2 = fmaf(wih2, x2, 0.0f);
        float a3 = 0.0f;
        #pragma unroll
        for (int j = 0; j < 16; ++j) {
            float4 hv = h4[j];
            a0 = fmaf(whh[4 * j + 0], hv.x, a0);
            a1 = fmaf(whh[4 * j + 1], hv.y, a1);
            a2 = fmaf(whh[4 * j + 2], hv.z, a2);
            a3 = fmaf(whh[4 * j + 3], hv.w, a3);
        }
        float acc = (a0 + a1) + (a2 + a3);

        float gval = gate_is_tanh ? tanh_(acc) : sigmoid_(acc);
        gates_lds[t & 1][tid] = gval;
        __syncthreads();   // single barrier: gates(t) visible to all waves

        // ---- phase B (all waves redundantly): update c[lane], h[lane] ----
        float gi = gates_lds[t & 1][0 * H_SZ + lane];
        float gf = gates_lds[t & 1][1 * H_SZ + lane];
        float gg = gates_lds[t & 1][2 * H_SZ + lane];
        float go = gates_lds[t & 1][3 * H_SZ + lane];
        c = fmaf(gf, c, gi * gg);
        float h = go * tanh_(c);
        h_lds[wv][lane] = h;      // own wave's copy; in-wave RAW handled by lgkmcnt

        if (t == next_cp) {       // block-uniform condition
            if (wv == 0) {
                float p = bproj_lds[lane];
                #pragma unroll 8
                for (int m = 0; m < H_SZ; ++m)
                    p = fmaf(wproj_lds[lane * 65 + m], h_lds[0][m], p);
                outb[cp_k * H_SZ + lane] = p;
            }
            next_cp += WSPF_;
            ++cp_k;
        }
        // no second barrier: gates double-buffer tolerates <=1-step wave skew
    }
}

extern "C" void kernel_launch(void* const* d_in, const int* in_sizes, int n_in,
                              void* d_out, int out_size, void* d_ws, size_t ws_size,
                              hipStream_t stream) {
    const float* wave_input  = (const float*)d_in[0];
    const float* wave_future = (const float*)d_in[1];
    const float* W_ih        = (const float*)d_in[2];
    const float* W_hh        = (const float*)d_in[3];
    const float* b_ih        = (const float*)d_in[4];
    const float* b_hh        = (const float*)d_in[5];
    const float* W_proj      = (const float*)d_in[6];
    const float* b_proj      = (const float*)d_in[7];
    float* out               = (float*)d_out;

    lstm_fused_kernel<<<BATCH, NGATES, 0, stream>>>(
        wave_input, wave_future, W_ih, W_hh, b_ih, b_hh, W_proj, b_proj, out);
}

// Round 3
// 1046.619 us; speedup vs baseline: 1.1288x; 1.1288x over previous
//
#include <hip/hip_runtime.h>
#include <math.h>

#define BATCH     512
#define T_PAST_   360
#define T_FUT_    1800
#define IN_SZ     3
#define H_SZ      64
#define FUT_SEQ   50
#define WSPF_     34
#define MAX_STEPS (FUT_SEQ * WSPF_)      // 1700
#define T_TOT     (T_PAST_ + MAX_STEPS)  // 2060
#define NTHREADS  256

// Partial-sum buffer: [kq_plane][gt][u], strides padded so phase-B reads
// (addr = gt*72 + u16 + col) land max 2-way per bank (gt*72 mod 32 = gt*8).
#define KQ_STRIDE 288        // 4 * GT_STRIDE
#define GT_STRIDE 72

__device__ __forceinline__ float rcp_(float x) {
    return __builtin_amdgcn_rcpf(x);     // v_rcp_f32, ~1ulp, plenty here
}

__device__ __forceinline__ float tanh_(float x) {
    float a = fabsf(x);
    float e = __expf(-2.0f * a);         // in (0,1], no overflow
    float t = (1.0f - e) * rcp_(1.0f + e);
    return copysignf(t, x);
}

__global__ __launch_bounds__(NTHREADS, 2)
void lstm_fused_kernel(const float* __restrict__ wave_input,   // [B, 360, 3]
                       const float* __restrict__ wave_future,  // [B, 1800, 3]
                       const float* __restrict__ W_ih,         // [256, 3]
                       const float* __restrict__ W_hh,         // [256, 64]
                       const float* __restrict__ b_ih,         // [256]
                       const float* __restrict__ b_hh,         // [256]
                       const float* __restrict__ W_proj,       // [64, 64]
                       const float* __restrict__ b_proj,       // [64]
                       float* __restrict__ out)                // [B, 50, 64]
{
    __shared__ __align__(16) float x_lds[T_TOT * IN_SZ];     // 24.7 KB
    __shared__ __align__(16) float wproj_lds[H_SZ * 65];     // 16.6 KB
    __shared__ __align__(16) float raw_lds[4 * KQ_STRIDE];   // 4.6 KB partial sums
    __shared__ __align__(16) float tmp_lds[4 * GT_STRIDE];   // activated gates
    __shared__ __align__(16) float h_lds[H_SZ];              // shared h
    __shared__ __align__(16) float bproj_lds[H_SZ];

    const int b    = blockIdx.x;
    const int tid  = threadIdx.x;
    const int wv   = tid >> 6;          // wave 0..3
    const int lane = tid & 63;
    const int col  = lane & 15;
    const int kq   = lane >> 4;         // phase A: k-slice; phase B: gate-type

    // ---- stage input sequence (coalesced) ----
    {
        const float* wi = wave_input + (size_t)b * (T_PAST_ * IN_SZ);
        for (int i = tid; i < T_PAST_ * IN_SZ; i += NTHREADS) x_lds[i] = wi[i];
        const float* wf = wave_future + (size_t)b * (T_FUT_ * IN_SZ);
        for (int i = tid; i < MAX_STEPS * IN_SZ; i += NTHREADS)
            x_lds[T_PAST_ * IN_SZ + i] = wf[i];
    }
    for (int i = tid; i < H_SZ * H_SZ; i += NTHREADS) {
        int r = i >> 6, cc = i & 63;
        wproj_lds[r * 65 + cc] = W_proj[i];
    }
    if (tid < H_SZ) { bproj_lds[tid] = b_proj[tid]; h_lds[tid] = 0.0f; }

    // ---- phase-A weights: gates g0..g0+3, k in [16kq, 16kq+16) -> 64 VGPR ----
    const int g0 = wv * 64 + col * 4;
    float whh[4][16];
    #pragma unroll
    for (int j = 0; j < 4; ++j) {
        const float4* wr = (const float4*)(W_hh + (size_t)(g0 + j) * H_SZ + kq * 16);
        #pragma unroll
        for (int q = 0; q < 4; ++q) {
            float4 v = wr[q];
            whh[j][4 * q + 0] = v.x; whh[j][4 * q + 1] = v.y;
            whh[j][4 * q + 2] = v.z; whh[j][4 * q + 3] = v.w;
        }
    }
    // ---- phase-B role: gate gB = kq*64 + u, unit u = 16*wv + col ----
    const int uIdx = 16 * wv + col;
    const int gB   = kq * H_SZ + uIdx;
    const float wihB0 = W_ih[gB * 3 + 0];
    const float wihB1 = W_ih[gB * 3 + 1];
    const float wihB2 = W_ih[gB * 3 + 2];
    const float biasB = b_ih[gB] + b_hh[gB];
    const bool  isg = (kq == 2);                 // g-gate -> tanh = 2*sig(2x)-1
    const float sc  = isg ? 2.0f : 1.0f;
    const float aa  = isg ? 2.0f : 1.0f;
    const float bb  = isg ? -1.0f : 0.0f;

    float c = 0.0f;                    // unit uIdx's cell state (x4 redundant)
    float* outb = out + (size_t)b * (FUT_SEQ * H_SZ);
    int next_cp = T_PAST_ + WSPF_ - 1;
    int cp_k = 0;

    __syncthreads();

    for (int t = 0; t < T_TOT; ++t) {
        // ---- phase A: partial gate sums over 16-wide k-slice ----
        const float4* h4 = (const float4*)(h_lds + kq * 16);
        float a0 = 0.f, a1 = 0.f, a2 = 0.f, a3 = 0.f;
        #pragma unroll
        for (int q = 0; q < 4; ++q) {
            float4 hv = h4[q];
            a0 = fmaf(whh[0][4*q+0], hv.x, a0); a0 = fmaf(whh[0][4*q+1], hv.y, a0);
            a0 = fmaf(whh[0][4*q+2], hv.z, a0); a0 = fmaf(whh[0][4*q+3], hv.w, a0);
            a1 = fmaf(whh[1][4*q+0], hv.x, a1); a1 = fmaf(whh[1][4*q+1], hv.y, a1);
            a1 = fmaf(whh[1][4*q+2], hv.z, a1); a1 = fmaf(whh[1][4*q+3], hv.w, a1);
            a2 = fmaf(whh[2][4*q+0], hv.x, a2); a2 = fmaf(whh[2][4*q+1], hv.y, a2);
            a2 = fmaf(whh[2][4*q+2], hv.z, a2); a2 = fmaf(whh[2][4*q+3], hv.w, a2);
            a3 = fmaf(whh[3][4*q+0], hv.x, a3); a3 = fmaf(whh[3][4*q+1], hv.y, a3);
            a3 = fmaf(whh[3][4*q+2], hv.z, a3); a3 = fmaf(whh[3][4*q+3], hv.w, a3);
        }
        *(float4*)(raw_lds + kq * KQ_STRIDE + wv * GT_STRIDE + col * 4)
            = make_float4(a0, a1, a2, a3);
        __syncthreads();                               // B1: partials ready

        // ---- phase B: one gate-activation per lane ----
        float s = raw_lds[0 * KQ_STRIDE + kq * GT_STRIDE + uIdx]
                + raw_lds[1 * KQ_STRIDE + kq * GT_STRIDE + uIdx]
                + raw_lds[2 * KQ_STRIDE + kq * GT_STRIDE + uIdx]
                + raw_lds[3 * KQ_STRIDE + kq * GT_STRIDE + uIdx];
        float x0 = x_lds[t * 3 + 0];
        float x1 = x_lds[t * 3 + 1];
        float x2 = x_lds[t * 3 + 2];
        float pre = fmaf(wihB0, x0, fmaf(wihB1, x1, fmaf(wihB2, x2, biasB + s)));
        float e   = __expf(-sc * pre);
        float act = aa * rcp_(1.0f + e) + bb;          // sigmoid / tanh unified
        tmp_lds[kq * GT_STRIDE + uIdx] = act;

        // gather i,f,g,o for unit uIdx (same-address broadcast among gt-group)
        float gi = tmp_lds[0 * GT_STRIDE + uIdx];
        float gf = tmp_lds[1 * GT_STRIDE + uIdx];
        float gg = tmp_lds[2 * GT_STRIDE + uIdx];
        float go = tmp_lds[3 * GT_STRIDE + uIdx];
        c = fmaf(gf, c, gi * gg);
        float h = go * tanh_(c);
        if (kq == 0) h_lds[uIdx] = h;                  // each wave: its 16 units
        __syncthreads();                               // B2: h ready

        if (t == next_cp) {                            // block-uniform
            if (wv == 0) {                             // lane = output unit j
                float p = bproj_lds[lane];
                #pragma unroll 8
                for (int m = 0; m < H_SZ; ++m)
                    p = fmaf(wproj_lds[lane * 65 + m], h_lds[m], p);
                outb[cp_k * H_SZ + lane] = p;
            }
            next_cp += WSPF_;
            ++cp_k;
        }
    }
}

extern "C" void kernel_launch(void* const* d_in, const int* in_sizes, int n_in,
                              void* d_out, int out_size, void* d_ws, size_t ws_size,
                              hipStream_t stream) {
    const float* wave_input  = (const float*)d_in[0];
    const float* wave_future = (const float*)d_in[1];
    const float* W_ih        = (const float*)d_in[2];
    const float* W_hh        = (const float*)d_in[3];
    const float* b_ih        = (const float*)d_in[4];
    const float* b_hh        = (const float*)d_in[5];
    const float* W_proj      = (const float*)d_in[6];
    const float* b_proj      = (const float*)d_in[7];
    float* out               = (float*)d_out;

    lstm_fused_kernel<<<BATCH, NTHREADS, 0, stream>>>(
        wave_input, wave_future, W_ih, W_hh, b_ih, b_hh, W_proj, b_proj, out);
}